// Round 3
// baseline (493.964 us; speedup 1.0000x reference)
//
#include <hip/hip_runtime.h>
#include <hip/hip_bf16.h>

#define L_ 4
#define B_ 256
#define C_ 512
#define N_ 50000
#define K_ 20
#define NLIST 21
#define NCH 64        // n-chunks per l
#define CHUNK 782     // ceil(50000/64)
#define LPAD 24
#define BIGF 3.0e38f
#define BN 128        // bank cols per n-tile
#define NKS 8         // K-steps (512/64)

// LDS byte offsets
#define QS0 0u         // 256 rows x 128B bf16
#define QS1 32768u
#define BS0 65536u     // 128 rows x 128B bf16
#define BS1 81920u
#define B2P_OFF 98304u // 1024 f32 partials
#define B2S_OFF 102400u// 128 f32
#define SMEM_BYTES 102912
// sd (256x65 f32 = 66560B) aliases QS0/QS1/BS0-head after K-loop
// mg (512x22 f32 = 45056B) aliases sd after last scan

typedef __attribute__((ext_vector_type(8))) short short8;
typedef __attribute__((ext_vector_type(4))) float f32x4;

__device__ __forceinline__ unsigned pk2(float lo, float hi) {
    __hip_bfloat162 h = __float22bfloat162_rn(make_float2(lo, hi));
    return *reinterpret_cast<unsigned*>(&h);
}

// ---------------- Phase 1: q (bf16) = mean_s feats ----------------
__global__ void qmean_kernel(const float* __restrict__ feats,
                             unsigned short* __restrict__ qbf)
{
    int gtid = blockIdx.x * 256 + threadIdx.x;
    int wid  = gtid >> 6;
    int lane = threadIdx.x & 63;
    const float4* src = reinterpret_cast<const float4*>(feats) + (size_t)wid * 64 + lane;
    float4 v = *src;
    float s = v.x + v.y + v.z + v.w;
    s += __shfl_xor(s, 1); s += __shfl_xor(s, 2);
    s += __shfl_xor(s, 4); s += __shfl_xor(s, 8);
    if ((lane & 15) == 0) {
        __hip_bfloat16 h = __float2bfloat16(s * (1.0f / 64.0f));
        qbf[wid * 4 + (lane >> 4)] = *reinterpret_cast<unsigned short*>(&h);
    }
}

// ---------------- Phase 2: pipelined MFMA cross-GEMM + top-21 ----------------
__global__ __launch_bounds__(512, 2)
void dist_topk_kernel(const float* __restrict__ bank,
                      const unsigned short* __restrict__ qbf,
                      float* __restrict__ lists)
{
    __shared__ __align__(16) unsigned char smem[SMEM_BYTES];

    const int tid = threadIdx.x;
    const int nc  = blockIdx.x & 63;
    const int l   = blockIdx.x >> 6;

    const unsigned short* qg = qbf + (size_t)l * B_ * C_;
    const float* bb = bank + (size_t)l * N_ * C_;

    const int n0 = nc * CHUNK;
    const int n1 = (n0 + CHUNK < N_) ? (n0 + CHUNK) : N_;

    const int lane = tid & 63;
    const int wid  = tid >> 6;
    const int wy   = wid >> 1;     // 0..3: 64-row band
    const int wx   = wid & 1;      // 0..1: 64-col half
    const int c_lo = lane & 15;
    const int r_hi = lane >> 4;
    const int c7   = c_lo & 7;

    // staging maps: slot i -> row=i>>3, phys 16B-slot=i&7 holds logical slot (i&7)^(row&7)
    int q_row[4], q_col[4]; unsigned q_lds[4];
#pragma unroll
    for (int j = 0; j < 4; ++j) {
        int i = tid + 512*j, r = i >> 3, sp = i & 7;
        q_row[j] = r; q_col[j] = (sp ^ (r & 7)) << 3; q_lds[j] = (unsigned)i << 4;
    }
    int b_row[2], b_col[2]; unsigned b_lds[2];
#pragma unroll
    for (int j = 0; j < 2; ++j) {
        int i = tid + 512*j, r = i >> 3, sp = i & 7;
        b_row[j] = r; b_col[j] = (sp ^ (r & 7)) << 3; b_lds[j] = (unsigned)i << 4;
    }

    // fragment read offsets (swizzled): row*128 + ((r_hi+4kh)^ (row&7)) * 16
    unsigned offA[4][2], offB[4][2];
#pragma unroll
    for (int m = 0; m < 4; ++m) {
        const int row = wy*64 + m*16 + c_lo;
#pragma unroll
        for (int kh = 0; kh < 2; ++kh)
            offA[m][kh] = (unsigned)(row*128 + (((r_hi + 4*kh) ^ c7) << 4));
    }
#pragma unroll
    for (int n = 0; n < 4; ++n) {
        const int row = wx*64 + n*16 + c_lo;
#pragma unroll
        for (int kh = 0; kh < 2; ++kh)
            offB[n][kh] = (unsigned)(row*128 + (((r_hi + 4*kh) ^ c7) << 4));
    }

    float list[NLIST];
#pragma unroll
    for (int i = 0; i < NLIST; ++i) list[i] = BIGF;

    float* b2p = reinterpret_cast<float*>(smem + B2P_OFF);
    float* b2v = reinterpret_cast<float*>(smem + B2S_OFF);
    float* sd  = reinterpret_cast<float*>(smem);

    for (int nt = n0; nt < n1; nt += BN) {
        const int ncols = (n1 - nt < BN) ? (n1 - nt) : BN;

        f32x4 acc[4][4];
#pragma unroll
        for (int m = 0; m < 4; ++m)
#pragma unroll
            for (int n = 0; n < 4; ++n) acc[m][n] = (f32x4){0.f, 0.f, 0.f, 0.f};

        float b2a0 = 0.f, b2a1 = 0.f;

        // ---- prologue: stage K-step 0 into buffer 0 ----
        {
            short8 qv[4]; float4 bv0[2], bv1[2];
#pragma unroll
            for (int j = 0; j < 4; ++j)
                qv[j] = *reinterpret_cast<const short8*>(qg + q_row[j]*C_ + q_col[j]);
#pragma unroll
            for (int j = 0; j < 2; ++j) {
                const int gr = nt + b_row[j];
                if (gr < n1) {
                    const float* src = bb + (size_t)gr*C_ + b_col[j];
                    bv0[j] = *reinterpret_cast<const float4*>(src);
                    bv1[j] = *reinterpret_cast<const float4*>(src + 4);
                } else {
                    bv0[j] = make_float4(0.f,0.f,0.f,0.f);
                    bv1[j] = make_float4(0.f,0.f,0.f,0.f);
                }
            }
#pragma unroll
            for (int j = 0; j < 4; ++j)
                *reinterpret_cast<short8*>(smem + QS0 + q_lds[j]) = qv[j];
#pragma unroll
            for (int j = 0; j < 2; ++j) {
                const float sq = bv0[j].x*bv0[j].x + bv0[j].y*bv0[j].y
                               + bv0[j].z*bv0[j].z + bv0[j].w*bv0[j].w
                               + bv1[j].x*bv1[j].x + bv1[j].y*bv1[j].y
                               + bv1[j].z*bv1[j].z + bv1[j].w*bv1[j].w;
                if (j == 0) b2a0 += sq; else b2a1 += sq;
                union { short8 s; unsigned u[4]; } pk;
                pk.u[0] = pk2(bv0[j].x, bv0[j].y);
                pk.u[1] = pk2(bv0[j].z, bv0[j].w);
                pk.u[2] = pk2(bv1[j].x, bv1[j].y);
                pk.u[3] = pk2(bv1[j].z, bv1[j].w);
                *reinterpret_cast<short8*>(smem + BS0 + b_lds[j]) = pk.s;
            }
        }
        __syncthreads();

        // ---- K loop: one barrier per step; loads for t+1 issued before MFMA(t) ----
        for (int ks = 0; ks < NKS; ++ks) {
            const int cur = ks & 1;
            const unsigned qsrc = cur ? QS1 : QS0;
            const unsigned bsrc = cur ? BS1 : BS0;
            const bool have = (ks + 1 < NKS);
            const int kb2 = (ks + 1) << 6;

            short8 qv[4]; float4 bv0[2], bv1[2];
            if (have) {
#pragma unroll
                for (int j = 0; j < 4; ++j)
                    qv[j] = *reinterpret_cast<const short8*>(qg + q_row[j]*C_ + kb2 + q_col[j]);
#pragma unroll
                for (int j = 0; j < 2; ++j) {
                    const int gr = nt + b_row[j];
                    if (gr < n1) {
                        const float* src = bb + (size_t)gr*C_ + kb2 + b_col[j];
                        bv0[j] = *reinterpret_cast<const float4*>(src);
                        bv1[j] = *reinterpret_cast<const float4*>(src + 4);
                    } else {
                        bv0[j] = make_float4(0.f,0.f,0.f,0.f);
                        bv1[j] = make_float4(0.f,0.f,0.f,0.f);
                    }
                }
            }

            short8 a[4][2];
#pragma unroll
            for (int m = 0; m < 4; ++m)
#pragma unroll
                for (int kh = 0; kh < 2; ++kh)
                    a[m][kh] = *reinterpret_cast<const short8*>(smem + qsrc + offA[m][kh]);
#pragma unroll
            for (int n = 0; n < 4; ++n) {
                const short8 b0 = *reinterpret_cast<const short8*>(smem + bsrc + offB[n][0]);
                const short8 b1 = *reinterpret_cast<const short8*>(smem + bsrc + offB[n][1]);
#pragma unroll
                for (int m = 0; m < 4; ++m) {
                    acc[m][n] = __builtin_amdgcn_mfma_f32_16x16x32_bf16(a[m][0], b0, acc[m][n], 0, 0, 0);
                    acc[m][n] = __builtin_amdgcn_mfma_f32_16x16x32_bf16(a[m][1], b1, acc[m][n], 0, 0, 0);
                }
            }

            if (have) {
                const unsigned qdst = cur ? QS0 : QS1;
                const unsigned bdst = cur ? BS0 : BS1;
#pragma unroll
                for (int j = 0; j < 4; ++j)
                    *reinterpret_cast<short8*>(smem + qdst + q_lds[j]) = qv[j];
#pragma unroll
                for (int j = 0; j < 2; ++j) {
                    const float sq = bv0[j].x*bv0[j].x + bv0[j].y*bv0[j].y
                                   + bv0[j].z*bv0[j].z + bv0[j].w*bv0[j].w
                                   + bv1[j].x*bv1[j].x + bv1[j].y*bv1[j].y
                                   + bv1[j].z*bv1[j].z + bv1[j].w*bv1[j].w;
                    if (j == 0) b2a0 += sq; else b2a1 += sq;
                    union { short8 s; unsigned u[4]; } pk;
                    pk.u[0] = pk2(bv0[j].x, bv0[j].y);
                    pk.u[1] = pk2(bv0[j].z, bv0[j].w);
                    pk.u[2] = pk2(bv1[j].x, bv1[j].y);
                    pk.u[3] = pk2(bv1[j].z, bv1[j].w);
                    *reinterpret_cast<short8*>(smem + bdst + b_lds[j]) = pk.s;
                }
            }
            __syncthreads();
        }

        // ---- deterministic b2 reduction ----
        b2p[tid]       = b2a0;
        b2p[tid + 512] = b2a1;
        __syncthreads();
        if (tid < 128) {
            const float* p = b2p + tid*8;
            b2v[tid] = ((p[0]+p[1]) + (p[2]+p[3])) + ((p[4]+p[5]) + (p[6]+p[7]));
        }
        __syncthreads();

        // ---- dump + scan, two 64-col halves (sd aliases staging buffers) ----
#pragma unroll 1
        for (int ph = 0; ph < 2; ++ph) {
            if (wx == ph) {
#pragma unroll
                for (int m = 0; m < 4; ++m)
#pragma unroll
                    for (int rg = 0; rg < 4; ++rg) {
                        const int row = wy*64 + m*16 + r_hi*4 + rg;
#pragma unroll
                        for (int n = 0; n < 4; ++n) {
                            const int lcol = n*16 + c_lo;
                            sd[row*65 + lcol] = b2v[ph*64 + lcol] - 2.0f * acc[m][n][rg];
                        }
                    }
            }
            __syncthreads();
            {
                const int r  = tid >> 1;
                const int cb = (tid & 1) << 5;
                const float* srow = sd + r*65 + cb;
                const int glim = ncols - ph*64 - cb;   // valid j < glim
#pragma unroll 4
                for (int j = 0; j < 32; ++j) {
                    if (j < glim) {
                        float v = srow[j];
                        if (v < list[NLIST-1]) {
#pragma unroll
                            for (int i = 0; i < NLIST; ++i) {
                                const float lo = fminf(list[i], v);
                                const float hi = fmaxf(list[i], v);
                                list[i] = lo; v = hi;
                            }
                        }
                    }
                }
            }
            __syncthreads();
        }
    }

    // ---- merge the 2 per-row sublists -> sorted 21, write to workspace ----
    float* mg = reinterpret_cast<float*>(smem);
#pragma unroll
    for (int i = 0; i < NLIST; ++i) mg[tid*22 + i] = list[i];
    __syncthreads();
    if ((tid & 1) == 0) {
        const int row = tid >> 1;
        float* outp = lists + ((size_t)(l*B_ + row)*NCH + nc)*LPAD;
        const float* g0 = mg + tid*22;
        const float* g1 = mg + (tid+1)*22;
        int p0 = 0, p1 = 0;
#pragma unroll 1
        for (int i = 0; i < NLIST; ++i) {
            const float h0 = (p0 < NLIST) ? g0[p0] : BIGF;
            const float h1 = (p1 < NLIST) ? g1[p1] : BIGF;
            if (h0 <= h1) { outp[i] = h0; ++p0; }
            else          { outp[i] = h1; ++p1; }
        }
    }
}

// ---------------- Phase 3: merge 64 sorted chunk-lists per (l,b), LID ----------------
__global__ void lid_kernel(const float* __restrict__ lists,
                           const unsigned short* __restrict__ qbf,
                           float* __restrict__ out)
{
    __shared__ float pops[4][NLIST];
    const int lane = threadIdx.x & 63;
    const int w    = threadIdx.x >> 6;
    const int gw   = blockIdx.x * 4 + w;   // 0..1023 = (l,b)
    const int l    = gw & 3;
    const int b    = gw >> 2;

    const unsigned short* qr = qbf + ((size_t)l*B_ + b)*C_;
    short8 qv = *reinterpret_cast<const short8*>(qr + lane*8);
    float q2 = 0.f;
#pragma unroll
    for (int i = 0; i < 8; ++i) {
        unsigned u = ((unsigned)(unsigned short)qv[i]) << 16;
        float f = __uint_as_float(u);
        q2 += f*f;
    }
    q2 += __shfl_xor(q2,1); q2 += __shfl_xor(q2,2); q2 += __shfl_xor(q2,4);
    q2 += __shfl_xor(q2,8); q2 += __shfl_xor(q2,16); q2 += __shfl_xor(q2,32);

    const float* lb = lists + ((size_t)(l*B_ + b)*NCH + lane)*LPAD;
    int ptr = 0;
#pragma unroll 1
    for (int i = 0; i < NLIST; ++i) {
        float h = (ptr < NLIST) ? lb[ptr] : BIGF;
        float m = h;
        m = fminf(m, __shfl_xor(m,1));  m = fminf(m, __shfl_xor(m,2));
        m = fminf(m, __shfl_xor(m,4));  m = fminf(m, __shfl_xor(m,8));
        m = fminf(m, __shfl_xor(m,16)); m = fminf(m, __shfl_xor(m,32));
        const unsigned long long ball = __ballot(h == m);
        if (lane == __ffsll(ball) - 1) ++ptr;
        if (lane == 0) pops[w][i] = fmaxf(q2 + m, 0.f);
    }
    __syncthreads();

    const float r2 = pops[w][NLIST-1];
    float t = 0.f;
    if (lane >= 1 && lane < NLIST) t = 0.5f * logf(pops[w][lane] / r2);
    t += __shfl_xor(t,1); t += __shfl_xor(t,2); t += __shfl_xor(t,4);
    t += __shfl_xor(t,8); t += __shfl_xor(t,16); t += __shfl_xor(t,32);

    if (lane == 0) out[(size_t)b * L_ + l] = -(float)K_ / t;
}

extern "C" void kernel_launch(void* const* d_in, const int* in_sizes, int n_in,
                              void* d_out, int out_size, void* d_ws, size_t ws_size,
                              hipStream_t stream)
{
    (void)in_sizes; (void)n_in; (void)out_size; (void)ws_size;
    const float* feats = (const float*)d_in[0];
    const float* bank  = (const float*)d_in[1];
    unsigned short* qbf = (unsigned short*)d_ws;                       // 1 MiB bf16 q
    float* lists = (float*)((char*)d_ws + (size_t)L_*B_*C_*2);         // 6 MiB chunk lists

    qmean_kernel<<<32768, 256, 0, stream>>>(feats, qbf);
    dist_topk_kernel<<<256, 512, 0, stream>>>(bank, qbf, lists);
    lid_kernel<<<256, 256, 0, stream>>>(lists, qbf, (float*)d_out);
}

// Round 4
// 313.839 us; speedup vs baseline: 1.5739x; 1.5739x over previous
//
#include <hip/hip_runtime.h>
#include <hip/hip_bf16.h>

#define L_ 4
#define B_ 256
#define C_ 512
#define N_ 50000
#define K_ 20
#define NLIST 21
#define NCH 48        // n-chunks per l
#define CHUNK 1042    // ceil(50000/48)
#define LPAD 24
#define BIGF 3.0e38f
#define BN 128        // bank cols per n-tile
#define KS 32         // K per step
#define NKS 16        // 512/32

// LDS byte offsets (per block)
#define QS0_O 0u       // 64 rows x 64B
#define QS1_O 4096u
#define BS0_O 8192u    // 128 rows x 64B
#define BS1_O 16384u
#define B2P_O 24576u   // 256 f32
#define B2V_O 25600u   // 128 f32
#define SMEM_BYTES 26112
// sd (64x65 f32 = 16640B) aliases staging @0 after K-loop
// mg (256x22 f32 = 22528B) aliases staging @0 after last scan

typedef __attribute__((ext_vector_type(8))) short short8;
typedef __attribute__((ext_vector_type(4))) float f32x4;

__device__ __forceinline__ unsigned pk2(float lo, float hi) {
    __hip_bfloat162 h = __float22bfloat162_rn(make_float2(lo, hi));
    return *reinterpret_cast<unsigned*>(&h);
}
__device__ __forceinline__ float sq4(float4 v) {
    return v.x*v.x + v.y*v.y + v.z*v.z + v.w*v.w;
}

// ---------------- Phase 1: q (bf16) = mean_s feats ----------------
__global__ void qmean_kernel(const float* __restrict__ feats,
                             unsigned short* __restrict__ qbf)
{
    int gtid = blockIdx.x * 256 + threadIdx.x;
    int wid  = gtid >> 6;
    int lane = threadIdx.x & 63;
    const float4* src = reinterpret_cast<const float4*>(feats) + (size_t)wid * 64 + lane;
    float4 v = *src;
    float s = v.x + v.y + v.z + v.w;
    s += __shfl_xor(s, 1); s += __shfl_xor(s, 2);
    s += __shfl_xor(s, 4); s += __shfl_xor(s, 8);
    if ((lane & 15) == 0) {
        __hip_bfloat16 h = __float2bfloat16(s * (1.0f / 64.0f));
        qbf[wid * 4 + (lane >> 4)] = *reinterpret_cast<unsigned short*>(&h);
    }
}

// ---------------- Phase 2: pipelined MFMA cross-GEMM + top-21 ----------------
__global__ __launch_bounds__(256, 3)
void dist_topk_kernel(const float* __restrict__ bank,
                      const unsigned short* __restrict__ qbf,
                      float* __restrict__ lists)
{
    __shared__ __align__(16) unsigned char smem[SMEM_BYTES];
    float* sd  = reinterpret_cast<float*>(smem);
    float* b2p = reinterpret_cast<float*>(smem + B2P_O);
    float* b2v = reinterpret_cast<float*>(smem + B2V_O);
    float* mg  = reinterpret_cast<float*>(smem);

    const int tid = threadIdx.x;
    // XCD-aware decode: 4 qh-partner blocks (same l,nc -> same bank stream)
    // get consecutive seq on the SAME XCD (hw round-robins blockIdx%8 -> XCD).
    const int bhw = blockIdx.x;           // 0..767
    const int xcd = bhw & 7;
    const int seq = bhw >> 3;             // 0..95
    const int grp = xcd * 24 + (seq >> 2);// 0..191 = (l,nc)
    const int qh  = seq & 3;
    const int l   = grp / NCH;
    const int nc  = grp - l * NCH;

    const unsigned short* qg = qbf + ((size_t)l * B_ + qh * 64) * C_;
    const float* bb = bank + (size_t)l * N_ * C_;
    const int n0 = nc * CHUNK;
    const int n1 = (n0 + CHUNK < N_) ? (n0 + CHUNK) : N_;

    const int lane = tid & 63;
    const int wid  = tid >> 6;
    const int wy   = wid >> 1;            // 0..1: 32-row band
    const int wx   = wid & 1;             // 0..1: 64-col half
    const int c_lo = lane & 15;
    const int r_hi = lane >> 4;

    // q staging: thread -> (row, phys 16B slot); phys p holds logical p^((row>>1)&3)
    const int qr  = tid >> 2;
    const int qk  = (((tid & 3) ^ ((qr >> 1) & 3)) << 3);   // logical k elem offset
    const unsigned qlds = (unsigned)tid << 4;
    // bank staging: thread -> row (tid>>1), 2 phys slots
    const int br  = tid >> 1;
    const int bp0 = (tid & 1) << 1;
    const int swb = (br >> 1) & 3;
    const int bk0 = ((bp0 ^ swb) << 3);
    const int bk1 = (((bp0 + 1) ^ swb) << 3);
    const unsigned blds = (unsigned)tid << 5;

    // fragment read offsets (swizzle-matched)
    unsigned offA[2], offB[4];
#pragma unroll
    for (int m = 0; m < 2; ++m) {
        const int row = wy*32 + m*16 + c_lo;
        offA[m] = (unsigned)(row*64 + ((r_hi ^ ((row >> 1) & 3)) << 4));
    }
#pragma unroll
    for (int n = 0; n < 4; ++n) {
        const int row = wx*64 + n*16 + c_lo;
        offB[n] = (unsigned)(row*64 + ((r_hi ^ ((row >> 1) & 3)) << 4));
    }

    float list[NLIST];
#pragma unroll
    for (int i = 0; i < NLIST; ++i) list[i] = BIGF;

    for (int nt = n0; nt < n1; nt += BN) {
        const int ncols = (n1 - nt < BN) ? (n1 - nt) : BN;

        f32x4 acc[2][4];
#pragma unroll
        for (int m = 0; m < 2; ++m)
#pragma unroll
            for (int n = 0; n < 4; ++n) acc[m][n] = (f32x4){0.f, 0.f, 0.f, 0.f};
        float b2a = 0.f;

        // ---- prologue: stage K-step 0 into buffer 0 ----
        {
            const short8 qv = *reinterpret_cast<const short8*>(qg + (size_t)qr * C_ + qk);
            const int gr = nt + br;
            float4 f0 = make_float4(0.f,0.f,0.f,0.f), f1 = f0, f2 = f0, f3 = f0;
            if (gr < n1) {
                const float* s0 = bb + (size_t)gr * C_ + bk0;
                const float* s1 = bb + (size_t)gr * C_ + bk1;
                f0 = *reinterpret_cast<const float4*>(s0);
                f1 = *reinterpret_cast<const float4*>(s0 + 4);
                f2 = *reinterpret_cast<const float4*>(s1);
                f3 = *reinterpret_cast<const float4*>(s1 + 4);
            }
            b2a += sq4(f0) + sq4(f1) + sq4(f2) + sq4(f3);
            *reinterpret_cast<short8*>(smem + QS0_O + qlds) = qv;
            union { short8 s; unsigned u[4]; } pa, pb;
            pa.u[0] = pk2(f0.x,f0.y); pa.u[1] = pk2(f0.z,f0.w);
            pa.u[2] = pk2(f1.x,f1.y); pa.u[3] = pk2(f1.z,f1.w);
            pb.u[0] = pk2(f2.x,f2.y); pb.u[1] = pk2(f2.z,f2.w);
            pb.u[2] = pk2(f3.x,f3.y); pb.u[3] = pk2(f3.z,f3.w);
            *reinterpret_cast<short8*>(smem + BS0_O + blds)      = pa.s;
            *reinterpret_cast<short8*>(smem + BS0_O + blds + 16) = pb.s;
        }
        __syncthreads();

        // ---- K loop: 1 barrier/step; t+1 loads issued before MFMA(t) ----
        for (int ks = 0; ks < NKS; ++ks) {
            const unsigned qsrc = (ks & 1) ? QS1_O : QS0_O;
            const unsigned bsrc = (ks & 1) ? BS1_O : BS0_O;
            const bool have = (ks + 1) < NKS;

            short8 qv;
            float4 f0 = make_float4(0.f,0.f,0.f,0.f), f1 = f0, f2 = f0, f3 = f0;
            if (have) {
                const int kb = (ks + 1) * KS;
                qv = *reinterpret_cast<const short8*>(qg + (size_t)qr * C_ + kb + qk);
                const int gr = nt + br;
                if (gr < n1) {
                    const float* s0 = bb + (size_t)gr * C_ + kb + bk0;
                    const float* s1 = bb + (size_t)gr * C_ + kb + bk1;
                    f0 = *reinterpret_cast<const float4*>(s0);
                    f1 = *reinterpret_cast<const float4*>(s0 + 4);
                    f2 = *reinterpret_cast<const float4*>(s1);
                    f3 = *reinterpret_cast<const float4*>(s1 + 4);
                }
            }

            const short8 a0 = *reinterpret_cast<const short8*>(smem + qsrc + offA[0]);
            const short8 a1 = *reinterpret_cast<const short8*>(smem + qsrc + offA[1]);
#pragma unroll
            for (int n = 0; n < 4; ++n) {
                const short8 bn = *reinterpret_cast<const short8*>(smem + bsrc + offB[n]);
                acc[0][n] = __builtin_amdgcn_mfma_f32_16x16x32_bf16(a0, bn, acc[0][n], 0, 0, 0);
                acc[1][n] = __builtin_amdgcn_mfma_f32_16x16x32_bf16(a1, bn, acc[1][n], 0, 0, 0);
            }

            if (have) {
                b2a += sq4(f0) + sq4(f1) + sq4(f2) + sq4(f3);
                const unsigned qd = (ks & 1) ? QS0_O : QS1_O;
                const unsigned bd = (ks & 1) ? BS0_O : BS1_O;
                *reinterpret_cast<short8*>(smem + qd + qlds) = qv;
                union { short8 s; unsigned u[4]; } pa, pb;
                pa.u[0] = pk2(f0.x,f0.y); pa.u[1] = pk2(f0.z,f0.w);
                pa.u[2] = pk2(f1.x,f1.y); pa.u[3] = pk2(f1.z,f1.w);
                pb.u[0] = pk2(f2.x,f2.y); pb.u[1] = pk2(f2.z,f2.w);
                pb.u[2] = pk2(f3.x,f3.y); pb.u[3] = pk2(f3.z,f3.w);
                *reinterpret_cast<short8*>(smem + bd + blds)      = pa.s;
                *reinterpret_cast<short8*>(smem + bd + blds + 16) = pb.s;
            }
            __syncthreads();
        }

        // ---- deterministic b2 reduction (thread pair per row) ----
        b2p[tid] = b2a;
        __syncthreads();
        if (tid < 128) b2v[tid] = b2p[2*tid] + b2p[2*tid + 1];
        __syncthreads();

        // ---- dump + scan, two 64-col phases (sd aliases staging) ----
#pragma unroll 1
        for (int ph = 0; ph < 2; ++ph) {
            if (wx == ph) {
                // C/D layout: col = lane&15, row = (lane>>4)*4 + reg
#pragma unroll
                for (int m = 0; m < 2; ++m)
#pragma unroll
                    for (int n = 0; n < 4; ++n) {
                        const int col = n*16 + c_lo;
                        const float bv = b2v[ph*64 + col];
#pragma unroll
                        for (int rg = 0; rg < 4; ++rg) {
                            const int row = wy*32 + m*16 + r_hi*4 + rg;
                            sd[row*65 + col] = bv - 2.0f * acc[m][n][rg];
                        }
                    }
            }
            __syncthreads();
            {
                const int r  = tid >> 2;
                const int cb = (tid & 3) << 4;
                const float* srow = sd + r*65 + cb;
                const int glim = ncols - ph*64 - cb;    // valid j < glim
#pragma unroll 4
                for (int j = 0; j < 16; ++j) {
                    if (j < glim) {
                        float v = srow[j];
                        if (v < list[NLIST - 1]) {
#pragma unroll
                            for (int i = 0; i < NLIST; ++i) {
                                const float lo = fminf(list[i], v);
                                const float hi = fmaxf(list[i], v);
                                list[i] = lo; v = hi;
                            }
                        }
                    }
                }
            }
            __syncthreads();
        }
    }

    // ---- merge 4 per-lane sublists per row -> sorted 21, write out ----
#pragma unroll
    for (int i = 0; i < NLIST; ++i) mg[tid*22 + i] = list[i];
    __syncthreads();
    if ((tid & 3) == 0) {
        const int row = tid >> 2;
        float* outp = lists + ((size_t)(l*B_ + qh*64 + row)*NCH + nc)*LPAD;
        int p0 = 0, p1 = 0, p2 = 0, p3 = 0;
#pragma unroll 1
        for (int i = 0; i < NLIST; ++i) {
            const float h0 = (p0 < NLIST) ? mg[(tid + 0)*22 + p0] : BIGF;
            const float h1 = (p1 < NLIST) ? mg[(tid + 1)*22 + p1] : BIGF;
            const float h2 = (p2 < NLIST) ? mg[(tid + 2)*22 + p2] : BIGF;
            const float h3 = (p3 < NLIST) ? mg[(tid + 3)*22 + p3] : BIGF;
            const float mv = fminf(fminf(h0, h1), fminf(h2, h3));
            if (h0 == mv)      ++p0;
            else if (h1 == mv) ++p1;
            else if (h2 == mv) ++p2;
            else               ++p3;
            outp[i] = mv;
        }
    }
}

// ---------------- Phase 3: merge 48 sorted chunk-lists per (l,b), LID ----------------
__global__ void lid_kernel(const float* __restrict__ lists,
                           const unsigned short* __restrict__ qbf,
                           float* __restrict__ out)
{
    __shared__ float pops[4][NLIST];
    const int lane = threadIdx.x & 63;
    const int w    = threadIdx.x >> 6;
    const int gw   = blockIdx.x * 4 + w;   // 0..1023 = (l,b)
    const int l    = gw & 3;
    const int b    = gw >> 2;

    const unsigned short* qr = qbf + ((size_t)l*B_ + b)*C_;
    short8 qv = *reinterpret_cast<const short8*>(qr + lane*8);
    float q2 = 0.f;
#pragma unroll
    for (int i = 0; i < 8; ++i) {
        unsigned u = ((unsigned)(unsigned short)qv[i]) << 16;
        float f = __uint_as_float(u);
        q2 += f*f;
    }
    q2 += __shfl_xor(q2,1); q2 += __shfl_xor(q2,2); q2 += __shfl_xor(q2,4);
    q2 += __shfl_xor(q2,8); q2 += __shfl_xor(q2,16); q2 += __shfl_xor(q2,32);

    const float* lb = lists + ((size_t)(l*B_ + b)*NCH + lane)*LPAD;
    int ptr = 0;
#pragma unroll 1
    for (int i = 0; i < NLIST; ++i) {
        float h = (lane < NCH && ptr < NLIST) ? lb[ptr] : BIGF;
        float m = h;
        m = fminf(m, __shfl_xor(m,1));  m = fminf(m, __shfl_xor(m,2));
        m = fminf(m, __shfl_xor(m,4));  m = fminf(m, __shfl_xor(m,8));
        m = fminf(m, __shfl_xor(m,16)); m = fminf(m, __shfl_xor(m,32));
        const unsigned long long ball = __ballot(h == m);
        if (lane == __ffsll(ball) - 1) ++ptr;
        if (lane == 0) pops[w][i] = fmaxf(q2 + m, 0.f);
    }
    __syncthreads();

    const float r2 = pops[w][NLIST-1];
    float t = 0.f;
    if (lane >= 1 && lane < NLIST) t = 0.5f * logf(pops[w][lane] / r2);
    t += __shfl_xor(t,1); t += __shfl_xor(t,2); t += __shfl_xor(t,4);
    t += __shfl_xor(t,8); t += __shfl_xor(t,16); t += __shfl_xor(t,32);

    if (lane == 0) out[(size_t)b * L_ + l] = -(float)K_ / t;
}

extern "C" void kernel_launch(void* const* d_in, const int* in_sizes, int n_in,
                              void* d_out, int out_size, void* d_ws, size_t ws_size,
                              hipStream_t stream)
{
    (void)in_sizes; (void)n_in; (void)out_size; (void)ws_size;
    const float* feats = (const float*)d_in[0];
    const float* bank  = (const float*)d_in[1];
    unsigned short* qbf = (unsigned short*)d_ws;                 // 1 MiB bf16 q
    float* lists = (float*)((char*)d_ws + (size_t)L_*B_*C_*2);   // ~4.7 MiB chunk lists

    qmean_kernel<<<32768, 256, 0, stream>>>(feats, qbf);
    dist_topk_kernel<<<768, 256, 0, stream>>>(bank, qbf, lists);
    lid_kernel<<<256, 256, 0, stream>>>(lists, qbf, (float*)d_out);
}

// Round 5
// 304.054 us; speedup vs baseline: 1.6246x; 1.0322x over previous
//
#include <hip/hip_runtime.h>
#include <hip/hip_bf16.h>

#define L_ 4
#define B_ 256
#define C_ 512
#define N_ 50000
#define K_ 20
#define NLIST 21
#define NCH 64        // n-chunks per l
#define CHUNK 782     // ceil(50000/64)
#define LPAD 21
#define BIGF 3.0e38f
#define BN 128        // bank cols per n-tile
#define KS 32         // K per step
#define NKS 16        // 512/32

// LDS byte offsets (per block)
#define QS0_O 0u       // 64 rows x 64B
#define QS1_O 4096u
#define BS0_O 8192u    // 128 rows x 64B
#define BS1_O 16384u
#define B2P_O 24576u   // 512 f32 partials
#define B2V_O 26624u   // 128 f32
#define SMEM_BYTES 27136
// sd (64 x 66 f32 = 16896B) aliases staging @0 after K-loop
// mg (256 x 22 f32 = 22528B) aliases staging @0 after last scan

typedef __attribute__((ext_vector_type(8))) short short8;
typedef __attribute__((ext_vector_type(4))) float f32x4;

__device__ __forceinline__ unsigned pk2(float lo, float hi) {
    __hip_bfloat162 h = __float22bfloat162_rn(make_float2(lo, hi));
    return *reinterpret_cast<unsigned*>(&h);
}
__device__ __forceinline__ float sq4(float4 v) {
    return v.x*v.x + v.y*v.y + v.z*v.z + v.w*v.w;
}

// ---------------- Phase 1: q (bf16) = mean_s feats ----------------
__global__ void qmean_kernel(const float* __restrict__ feats,
                             unsigned short* __restrict__ qbf)
{
    int gtid = blockIdx.x * 256 + threadIdx.x;
    int wid  = gtid >> 6;
    int lane = threadIdx.x & 63;
    const float4* src = reinterpret_cast<const float4*>(feats) + (size_t)wid * 64 + lane;
    float4 v = *src;
    float s = v.x + v.y + v.z + v.w;
    s += __shfl_xor(s, 1); s += __shfl_xor(s, 2);
    s += __shfl_xor(s, 4); s += __shfl_xor(s, 8);
    if ((lane & 15) == 0) {
        __hip_bfloat16 h = __float2bfloat16(s * (1.0f / 64.0f));
        qbf[wid * 4 + (lane >> 4)] = *reinterpret_cast<unsigned short*>(&h);
    }
}

// ---------------- Phase 2: pipelined MFMA cross-GEMM + top-21 ----------------
__global__ __launch_bounds__(256, 4)
void dist_topk_kernel(const float* __restrict__ bank,
                      const unsigned short* __restrict__ qbf,
                      float* __restrict__ lists)
{
    __shared__ __align__(16) unsigned char smem[SMEM_BYTES];
    float* sd  = reinterpret_cast<float*>(smem);
    float* b2p = reinterpret_cast<float*>(smem + B2P_O);
    float* b2v = reinterpret_cast<float*>(smem + B2V_O);
    float* mg  = reinterpret_cast<float*>(smem);

    const int tid = threadIdx.x;
    // XCD-aware decode: 4 qh-partner blocks (same l,nc -> same bank stream)
    // land consecutively on the SAME XCD (hw round-robins blockIdx%8 -> XCD).
    const int bhw = blockIdx.x;            // 0..1023
    const int xcd = bhw & 7;
    const int seq = bhw >> 3;              // 0..127
    const int grp = xcd * 32 + (seq >> 2); // 0..255 = (l,nc)
    const int qh  = seq & 3;
    const int l   = grp >> 6;
    const int nc  = grp & 63;

    const unsigned short* qg = qbf + ((size_t)l * B_ + qh * 64) * C_;
    const float* bb = bank + (size_t)l * N_ * C_;
    const int n0 = nc * CHUNK;
    const int n1 = (n0 + CHUNK < N_) ? (n0 + CHUNK) : N_;

    const int lane = tid & 63;
    const int wid  = tid >> 6;
    const int wy   = wid >> 1;             // 0..1: 32-row band
    const int wx   = wid & 1;              // 0..1: 64-col half
    const int c_lo = lane & 15;
    const int r_hi = lane >> 4;

    // q staging: thread -> (row=tid>>2, phys slot tid&3); phys p holds logical p^((row>>1)&3)
    const int qr  = tid >> 2;
    const int qk  = (((tid & 3) ^ ((tid >> 3) & 3)) << 3);
    const unsigned qlds = (unsigned)tid << 4;
    // bank staging: thread t -> slots t (row t>>2) and t+256 (row 64+(t>>2)), same kseg
    const int br  = tid >> 2;              // local row (and +64)
    const int bk  = (((tid & 3) ^ ((tid >> 3) & 3)) << 3);
    const unsigned blds0 = (unsigned)tid << 4;           // byte 16t
    const unsigned blds1 = ((unsigned)tid << 4) + 4096u; // byte 16t + 4096

    // fragment read offsets (swizzle-matched)
    unsigned offA[2], offB[4];
#pragma unroll
    for (int m = 0; m < 2; ++m) {
        const int row = wy*32 + m*16 + c_lo;
        offA[m] = (unsigned)(row*64 + ((r_hi ^ ((row >> 1) & 3)) << 4));
    }
#pragma unroll
    for (int n = 0; n < 4; ++n) {
        const int row = wx*64 + n*16 + c_lo;
        offB[n] = (unsigned)(row*64 + ((r_hi ^ ((row >> 1) & 3)) << 4));
    }

    float list[NLIST];
#pragma unroll
    for (int i = 0; i < NLIST; ++i) list[i] = BIGF;

    for (int nt = n0; nt < n1; nt += BN) {
        const int ncols = (n1 - nt < BN) ? (n1 - nt) : BN;

        f32x4 acc[2][4];
#pragma unroll
        for (int m = 0; m < 2; ++m)
#pragma unroll
            for (int n = 0; n < 4; ++n) acc[m][n] = (f32x4){0.f, 0.f, 0.f, 0.f};
        float b2a0 = 0.f, b2a1 = 0.f;

        // ---- prologue: stage K-step 0 into buffer 0 ----
        {
            const short8 qv = *reinterpret_cast<const short8*>(qg + (size_t)qr * C_ + qk);
            const int gr0 = nt + br, gr1 = gr0 + 64;
            float4 f0 = make_float4(0.f,0.f,0.f,0.f), f1 = f0, f2 = f0, f3 = f0;
            if (gr0 < n1) {
                const float* s0 = bb + (size_t)gr0 * C_ + bk;
                f0 = *reinterpret_cast<const float4*>(s0);
                f1 = *reinterpret_cast<const float4*>(s0 + 4);
            }
            if (gr1 < n1) {
                const float* s1 = bb + (size_t)gr1 * C_ + bk;
                f2 = *reinterpret_cast<const float4*>(s1);
                f3 = *reinterpret_cast<const float4*>(s1 + 4);
            }
            b2a0 += sq4(f0) + sq4(f1);
            b2a1 += sq4(f2) + sq4(f3);
            *reinterpret_cast<short8*>(smem + QS0_O + qlds) = qv;
            union { short8 s; unsigned u[4]; } pa, pb;
            pa.u[0] = pk2(f0.x,f0.y); pa.u[1] = pk2(f0.z,f0.w);
            pa.u[2] = pk2(f1.x,f1.y); pa.u[3] = pk2(f1.z,f1.w);
            pb.u[0] = pk2(f2.x,f2.y); pb.u[1] = pk2(f2.z,f2.w);
            pb.u[2] = pk2(f3.x,f3.y); pb.u[3] = pk2(f3.z,f3.w);
            *reinterpret_cast<short8*>(smem + BS0_O + blds0) = pa.s;
            *reinterpret_cast<short8*>(smem + BS0_O + blds1) = pb.s;
        }
        __syncthreads();

        // ---- K loop: 1 barrier/step; t+1 loads issued before MFMA(t) ----
        for (int ks = 0; ks < NKS; ++ks) {
            const unsigned qsrc = (ks & 1) ? QS1_O : QS0_O;
            const unsigned bsrc = (ks & 1) ? BS1_O : BS0_O;
            const bool have = (ks + 1) < NKS;

            short8 qv;
            float4 f0 = make_float4(0.f,0.f,0.f,0.f), f1 = f0, f2 = f0, f3 = f0;
            if (have) {
                const int kb = (ks + 1) * KS;
                qv = *reinterpret_cast<const short8*>(qg + (size_t)qr * C_ + kb + qk);
                const int gr0 = nt + br, gr1 = gr0 + 64;
                if (gr0 < n1) {
                    const float* s0 = bb + (size_t)gr0 * C_ + kb + bk;
                    f0 = *reinterpret_cast<const float4*>(s0);
                    f1 = *reinterpret_cast<const float4*>(s0 + 4);
                }
                if (gr1 < n1) {
                    const float* s1 = bb + (size_t)gr1 * C_ + kb + bk;
                    f2 = *reinterpret_cast<const float4*>(s1);
                    f3 = *reinterpret_cast<const float4*>(s1 + 4);
                }
            }

            const short8 a0 = *reinterpret_cast<const short8*>(smem + qsrc + offA[0]);
            const short8 a1 = *reinterpret_cast<const short8*>(smem + qsrc + offA[1]);
#pragma unroll
            for (int n = 0; n < 4; ++n) {
                const short8 bn = *reinterpret_cast<const short8*>(smem + bsrc + offB[n]);
                acc[0][n] = __builtin_amdgcn_mfma_f32_16x16x32_bf16(a0, bn, acc[0][n], 0, 0, 0);
                acc[1][n] = __builtin_amdgcn_mfma_f32_16x16x32_bf16(a1, bn, acc[1][n], 0, 0, 0);
            }

            if (have) {
                b2a0 += sq4(f0) + sq4(f1);
                b2a1 += sq4(f2) + sq4(f3);
                const unsigned qd = (ks & 1) ? QS0_O : QS1_O;
                const unsigned bd = (ks & 1) ? BS0_O : BS1_O;
                *reinterpret_cast<short8*>(smem + qd + qlds) = qv;
                union { short8 s; unsigned u[4]; } pa, pb;
                pa.u[0] = pk2(f0.x,f0.y); pa.u[1] = pk2(f0.z,f0.w);
                pa.u[2] = pk2(f1.x,f1.y); pa.u[3] = pk2(f1.z,f1.w);
                pb.u[0] = pk2(f2.x,f2.y); pb.u[1] = pk2(f2.z,f2.w);
                pb.u[2] = pk2(f3.x,f3.y); pb.u[3] = pk2(f3.z,f3.w);
                *reinterpret_cast<short8*>(smem + bd + blds0) = pa.s;
                *reinterpret_cast<short8*>(smem + bd + blds1) = pb.s;
            }
            __syncthreads();
        }

        // ---- deterministic b2 reduction ----
        // thread t produced col (t>>2) part (t&3), and col 64+(t>>2) part (t&3)
        b2p[((unsigned)tid & 1023)]      = b2a0;   // col*4+part = tid
        b2p[((unsigned)tid & 1023)+256]  = b2a1;   // (64+col)*4+part = tid+256
        __syncthreads();
        if (tid < 128) {
            const float* p = b2p + tid*4;
            b2v[tid] = (p[0] + p[1]) + (p[2] + p[3]);
        }
        __syncthreads();

        // ---- dump + scan, two 64-col phases (sd aliases staging) ----
#pragma unroll 1
        for (int ph = 0; ph < 2; ++ph) {
            const int lim = ncols - ph*64;    // cols < lim are valid this phase
            if (wx == ph) {
                // C/D layout: col = lane&15, row = (lane>>4)*4 + reg
#pragma unroll
                for (int m = 0; m < 2; ++m)
#pragma unroll
                    for (int n = 0; n < 4; ++n) {
                        const int col = n*16 + c_lo;
                        const float bv = b2v[ph*64 + col];
                        const bool ok = col < lim;
#pragma unroll
                        for (int rg = 0; rg < 4; ++rg) {
                            const int row = wy*32 + m*16 + r_hi*4 + rg;
                            const float v = fmaf(-2.0f, acc[m][n][rg], bv);
                            sd[row*66 + col] = ok ? v : BIGF;
                        }
                    }
            }
            __syncthreads();
            {
                const int r  = tid >> 2;
                const int cb = tid & 3;
                const float* srow = sd + r*66 + (cb << 4);
#pragma unroll
                for (int bt = 0; bt < 4; ++bt) {
                    const float2 u = *reinterpret_cast<const float2*>(srow + (bt << 2));
                    const float2 w = *reinterpret_cast<const float2*>(srow + (bt << 2) + 2);
                    const float m4 = fminf(fminf(u.x, u.y), fminf(w.x, w.y));
                    if (m4 < list[NLIST-1]) {
                        float cand[4] = {u.x, u.y, w.x, w.y};
#pragma unroll
                        for (int c4 = 0; c4 < 4; ++c4) {
                            float v = cand[c4];
                            if (v < list[NLIST-1]) {
#pragma unroll
                                for (int i = 0; i < NLIST; ++i) {
                                    const float lo = fminf(list[i], v);
                                    const float hi = fmaxf(list[i], v);
                                    list[i] = lo; v = hi;
                                }
                            }
                        }
                    }
                }
            }
            __syncthreads();
        }
    }

    // ---- merge 4 per-lane sublists per row -> sorted 21, write out ----
#pragma unroll
    for (int i = 0; i < NLIST; ++i) mg[tid*22 + i] = list[i];
    __syncthreads();
    if ((tid & 3) == 0) {
        const int row = tid >> 2;
        float* outp = lists + ((size_t)(l*B_ + qh*64 + row)*NCH + nc)*LPAD;
        int p0 = 0, p1 = 0, p2 = 0, p3 = 0;
#pragma unroll 1
        for (int i = 0; i < NLIST; ++i) {
            const float h0 = (p0 < NLIST) ? mg[(tid + 0)*22 + p0] : BIGF;
            const float h1 = (p1 < NLIST) ? mg[(tid + 1)*22 + p1] : BIGF;
            const float h2 = (p2 < NLIST) ? mg[(tid + 2)*22 + p2] : BIGF;
            const float h3 = (p3 < NLIST) ? mg[(tid + 3)*22 + p3] : BIGF;
            const float mv = fminf(fminf(h0, h1), fminf(h2, h3));
            if (h0 == mv)      ++p0;
            else if (h1 == mv) ++p1;
            else if (h2 == mv) ++p2;
            else               ++p3;
            outp[i] = mv;
        }
    }
}

// ---------------- Phase 3: merge 64 sorted chunk-lists per (l,b), LID ----------------
__global__ void lid_kernel(const float* __restrict__ lists,
                           const unsigned short* __restrict__ qbf,
                           float* __restrict__ out)
{
    __shared__ float pops[4][NLIST];
    const int lane = threadIdx.x & 63;
    const int w    = threadIdx.x >> 6;
    const int gw   = blockIdx.x * 4 + w;   // 0..1023 = (l,b)
    const int l    = gw & 3;
    const int b    = gw >> 2;

    const unsigned short* qr = qbf + ((size_t)l*B_ + b)*C_;
    short8 qv = *reinterpret_cast<const short8*>(qr + lane*8);
    float q2 = 0.f;
#pragma unroll
    for (int i = 0; i < 8; ++i) {
        unsigned u = ((unsigned)(unsigned short)qv[i]) << 16;
        float f = __uint_as_float(u);
        q2 += f*f;
    }
    q2 += __shfl_xor(q2,1); q2 += __shfl_xor(q2,2); q2 += __shfl_xor(q2,4);
    q2 += __shfl_xor(q2,8); q2 += __shfl_xor(q2,16); q2 += __shfl_xor(q2,32);

    const float* lb = lists + ((size_t)(l*B_ + b)*NCH + lane)*LPAD;
    int ptr = 0;
#pragma unroll 1
    for (int i = 0; i < NLIST; ++i) {
        float h = (ptr < NLIST) ? lb[ptr] : BIGF;
        float m = h;
        m = fminf(m, __shfl_xor(m,1));  m = fminf(m, __shfl_xor(m,2));
        m = fminf(m, __shfl_xor(m,4));  m = fminf(m, __shfl_xor(m,8));
        m = fminf(m, __shfl_xor(m,16)); m = fminf(m, __shfl_xor(m,32));
        const unsigned long long ball = __ballot(h == m);
        if (lane == __ffsll(ball) - 1) ++ptr;
        if (lane == 0) pops[w][i] = fmaxf(q2 + m, 0.f);
    }
    __syncthreads();

    const float r2 = pops[w][NLIST-1];
    float t = 0.f;
    if (lane >= 1 && lane < NLIST) t = 0.5f * logf(pops[w][lane] / r2);
    t += __shfl_xor(t,1); t += __shfl_xor(t,2); t += __shfl_xor(t,4);
    t += __shfl_xor(t,8); t += __shfl_xor(t,16); t += __shfl_xor(t,32);

    if (lane == 0) out[(size_t)b * L_ + l] = -(float)K_ / t;
}

extern "C" void kernel_launch(void* const* d_in, const int* in_sizes, int n_in,
                              void* d_out, int out_size, void* d_ws, size_t ws_size,
                              hipStream_t stream)
{
    (void)in_sizes; (void)n_in; (void)out_size; (void)ws_size;
    const float* feats = (const float*)d_in[0];
    const float* bank  = (const float*)d_in[1];
    unsigned short* qbf = (unsigned short*)d_ws;                 // 1 MiB bf16 q
    float* lists = (float*)((char*)d_ws + (size_t)L_*B_*C_*2);   // ~5.5 MiB chunk lists

    qmean_kernel<<<32768, 256, 0, stream>>>(feats, qbf);
    dist_topk_kernel<<<1024, 256, 0, stream>>>(bank, qbf, lists);
    lid_kernel<<<256, 256, 0, stream>>>(lists, qbf, (float*)d_out);
}